// Round 1
// 492.038 us; speedup vs baseline: 1.1492x; 1.1492x over previous
//
#include <hip/hip_runtime.h>

#define HID 2048
#define NTHREADS 256

typedef float f32x4 __attribute__((ext_vector_type(4)));

// One block per token t in [0, T).  Layouts (fp32):
//   hs  [4, T, HID], act [T, HID], rns [HID], rw [HID,4],
//   pw  [4,16], cw [4,4], cscale [HID], out [4, T, HID]
//
// Each thread owns TWO float4 chunks at c0 = tid*4 and c1 = 1024 + tid*4.
// => every load/store instruction is fully contiguous across the block
//    (256 lanes x 16B = 4KB, full 64B cachelines per instruction).
__global__ __launch_bounds__(NTHREADS) void altup_fused(
    const float* __restrict__ hs,
    const float* __restrict__ act,
    const float* __restrict__ rns,
    const float* __restrict__ rw,
    const float* __restrict__ pw,
    const float* __restrict__ cw,
    const float* __restrict__ cscale,
    float* __restrict__ out,
    int T)
{
    const int t   = blockIdx.x;
    const int tid = threadIdx.x;
    const int c0  = tid * 4;          // chunk 0: floats [0, 1024)
    const int c1  = c0 + 1024;        // chunk 1: floats [1024, 2048)

    __shared__ float s_red[4][10];

    const size_t tok     = (size_t)t * HID;
    const size_t strideN = (size_t)T * HID;

    // ---- phase 1 loads (fully coalesced per instruction) ----
    float x0a[4], x0b[4], aa[4], ab[4], nsa[4], nsb[4], wa[16], wb[16];
    *(f32x4*)x0a = *(const f32x4*)(hs  + tok + c0);
    *(f32x4*)x0b = *(const f32x4*)(hs  + tok + c1);
    *(f32x4*)aa  = *(const f32x4*)(act + tok + c0);
    *(f32x4*)ab  = *(const f32x4*)(act + tok + c1);
    *(f32x4*)nsa = *(const f32x4*)(rns + c0);
    *(f32x4*)nsb = *(const f32x4*)(rns + c1);
    #pragma unroll
    for (int r = 0; r < 4; ++r) {
        *(f32x4*)(wa + 4 * r) = *(const f32x4*)(rw + (size_t)(c0 + r) * 4);
        *(f32x4*)(wb + 4 * r) = *(const f32x4*)(rw + (size_t)(c1 + r) * 4);
    }

    // ---- partial reductions over the 8 owned h positions ----
    float red[10];
    #pragma unroll
    for (int k = 0; k < 10; ++k) red[k] = 0.f;
    #pragma unroll
    for (int j = 0; j < 4; ++j) {
        float x0 = x0a[j], a = aa[j], ns = nsa[j];
        red[0] += x0 * x0;
        red[1] += a * a;
        float xs = x0 * ns, as_ = a * ns;
        #pragma unroll
        for (int n = 0; n < 4; ++n) {
            red[2 + n] += xs  * wa[4 * j + n];
            red[6 + n] += as_ * wa[4 * j + n];
        }
    }
    #pragma unroll
    for (int j = 0; j < 4; ++j) {
        float x0 = x0b[j], a = ab[j], ns = nsb[j];
        red[0] += x0 * x0;
        red[1] += a * a;
        float xs = x0 * ns, as_ = a * ns;
        #pragma unroll
        for (int n = 0; n < 4; ++n) {
            red[2 + n] += xs  * wb[4 * j + n];
            red[6 + n] += as_ * wb[4 * j + n];
        }
    }

    // ---- issue phase-2 loads NOW: HBM latency overlaps shuffles+barrier ----
    float x1a[4], x1b[4], x2a[4], x2b[4], x3a[4], x3b[4], csa[4], csb[4];
    *(f32x4*)x1a = *(const f32x4*)(hs + 1 * strideN + tok + c0);
    *(f32x4*)x1b = *(const f32x4*)(hs + 1 * strideN + tok + c1);
    *(f32x4*)x2a = *(const f32x4*)(hs + 2 * strideN + tok + c0);
    *(f32x4*)x2b = *(const f32x4*)(hs + 2 * strideN + tok + c1);
    *(f32x4*)x3a = *(const f32x4*)(hs + 3 * strideN + tok + c0);
    *(f32x4*)x3b = *(const f32x4*)(hs + 3 * strideN + tok + c1);
    *(f32x4*)csa = *(const f32x4*)(cscale + c0);
    *(f32x4*)csb = *(const f32x4*)(cscale + c1);

    // ---- wave(64) butterfly, ONE barrier, then all threads finish redundantly ----
    #pragma unroll
    for (int off = 32; off > 0; off >>= 1) {
        #pragma unroll
        for (int k = 0; k < 10; ++k) red[k] += __shfl_down(red[k], off, 64);
    }
    const int wave = tid >> 6, lane = tid & 63;
    if (lane == 0) {
        #pragma unroll
        for (int k = 0; k < 10; ++k) s_red[wave][k] = red[k];
    }
    __syncthreads();

    float acc[10];
    #pragma unroll
    for (int k = 0; k < 10; ++k)
        acc[k] = s_red[0][k] + s_red[1][k] + s_red[2][k] + s_red[3][k];

    const float invH  = 1.0f / (float)HID;
    const float inv_p = rsqrtf(acc[0] * invH + 1e-6f) * invH;
    const float inv_c = rsqrtf(acc[1] * invH + 1e-6f) * invH;
    float mp[4], mc[4];
    #pragma unroll
    for (int n = 0; n < 4; ++n) {
        mp[n] = tanhf(acc[2 + n] * inv_p);
        mc[n] = tanhf(acc[6 + n] * inv_c);
    }
    // pw/cw are uniform-address reads -> scalar loads, L2-resident
    float raw[16];
    #pragma unroll
    for (int kk = 0; kk < 16; ++kk)
        raw[kk] = mp[0] * pw[kk]      + mp[1] * pw[16 + kk]
                + mp[2] * pw[32 + kk] + mp[3] * pw[48 + kk];
    float coef[4];
    #pragma unroll
    for (int m = 0; m < 4; ++m)
        coef[m] = 1.0f + mc[0] * cw[m]     + mc[1] * cw[4 + m]
                       + mc[2] * cw[8 + m] + mc[3] * cw[12 + m];

    // ---- phase 2: elementwise, nontemporal full-line stores ----
    auto emit = [&](const float* x0, const float* x1, const float* x2,
                    const float* x3, const float* a, const float* cs,
                    size_t off) {
        float o[4][4];
        #pragma unroll
        for (int j = 0; j < 4; ++j) {
            float x[4] = { x0[j], x1[j], x2[j], x3[j] };
            float pred[4];
            #pragma unroll
            for (int m = 0; m < 4; ++m)
                pred[m] = x[0] * raw[4 * m + 0] + x[1] * raw[4 * m + 1]
                        + x[2] * raw[4 * m + 2] + x[3] * raw[4 * m + 3] + x[m];
            float innov = a[j] - pred[0];
            #pragma unroll
            for (int m = 0; m < 4; ++m)
                o[m][j] = (pred[m] + innov * coef[m]) * cs[j];
        }
        #pragma unroll
        for (int m = 0; m < 4; ++m)
            __builtin_nontemporal_store(*(const f32x4*)o[m],
                                        (f32x4*)(out + (size_t)m * strideN + off));
    };
    emit(x0a, x1a, x2a, x3a, aa, csa, tok + c0);
    emit(x0b, x1b, x2b, x3b, ab, csb, tok + c1);
}

extern "C" void kernel_launch(void* const* d_in, const int* in_sizes, int n_in,
                              void* d_out, int out_size, void* d_ws, size_t ws_size,
                              hipStream_t stream) {
    const float* hs  = (const float*)d_in[0]; // [4,B,S,H]
    const float* act = (const float*)d_in[1]; // [B,S,H]
    const float* rns = (const float*)d_in[2]; // [H]
    const float* rw  = (const float*)d_in[3]; // [H,4]
    const float* pw  = (const float*)d_in[4]; // [4,16]
    const float* cw  = (const float*)d_in[5]; // [4,4]
    const float* cs  = (const float*)d_in[6]; // [H]
    float* out = (float*)d_out;               // [4,B,S,H]

    const int T = in_sizes[1] / HID;  // B*S tokens
    altup_fused<<<dim3(T), dim3(NTHREADS), 0, stream>>>(hs, act, rns, rw, pw, cw, cs, out, T);
}